// Round 1
// baseline (129.312 us; speedup 1.0000x reference)
//
#include <hip/hip_runtime.h>
#include <stdint.h>

// S=4096, D=64.  out = (t * floor(t*rr)/R) @ V,  t = (QK^T*8) * dropout_keep/0.9
// R13 = R12 with the dropout mask PRECOMPUTED as a 2MB row-major bitmask in
// prep_all (streaming 64MB f32 -> 1 bit/elem at ~6.3TB/s), so fused_main no
// longer streams Ud on its latency-bound critical path. Per tile each lane
// loads one int4 (128 bits) per accumulator row (4 loads/lane/tile, double-
// buffered cross-iteration); bit for acc[rg] at col cs*16+n16 is bit
// (cs&1)*16+n16 of word cs>>1 (compile-time word select). Removes the 8
// u-float4 loads, the 64-op pack, and 32 ds_bpermute per tile. Counted drain
// becomes vmcnt(8): youngest = mask(t+1) 4 + K(t+1) 4.

#define S 4096
#define D 64
#define NCHUNK 8              // grid = 64 i-blocks * 8 chunks = 512 blocks
#define JCHUNK (S / NCHUNK)   // 512
#define JT 128
#define NTILES (JCHUNK / JT)  // 4
#define LDP 132               // pb pitch (shorts): 4 quads -> 4 distinct bank groups
#define KSCALE (8.0f / 0.9f)
#define MASKB 2048            // mask-producer blocks (524288 words / 256)

typedef float f32x4 __attribute__((ext_vector_type(4)));
typedef short s16x8 __attribute__((ext_vector_type(8)));
typedef unsigned short u16x4 __attribute__((ext_vector_type(4)));
typedef int i32x4 __attribute__((ext_vector_type(4)));
typedef const __attribute__((address_space(1))) unsigned g_u32;
typedef __attribute__((address_space(3))) unsigned lds_u32;

__device__ inline unsigned short f2bf(float f) {
    union { float f; unsigned u; } v; v.f = f;
    unsigned r = v.u + 0x7fffu + ((v.u >> 16) & 1u);
    return (unsigned short)(r >> 16);
}

// ---- prep: mask bits (blocks 0..2047), Q/K->bf16 (2048..2559), V->V^T (2560..2623)
__global__ void prep_all(const float* __restrict__ Q,
                         const float* __restrict__ Kf,
                         const float* __restrict__ V,
                         const float* __restrict__ Ud,
                         short* __restrict__ Qbf, short* __restrict__ Kbf,
                         short* __restrict__ VTbf,
                         unsigned* __restrict__ PM, int* __restrict__ sumr) {
    __shared__ short tile[64 * 68];
    const int b   = blockIdx.x;
    const int tid = threadIdx.x;
    if (b == 0 && tid == 0) *sumr = 0;

    if (b < MASKB) {
        // one u32 mask word (32 consecutive floats) per thread; 64MB streamed
        const int wi = b * 256 + tid;                 // 524288 words
        const float4* src = (const float4*)Ud + (size_t)wi * 8;
        unsigned m = 0;
#pragma unroll
        for (int q = 0; q < 8; ++q) {
            const float4 v = src[q];
            m |= (v.x >= 0.1f ? 1u : 0u) << (q * 4 + 0);
            m |= (v.y >= 0.1f ? 1u : 0u) << (q * 4 + 1);
            m |= (v.z >= 0.1f ? 1u : 0u) << (q * 4 + 2);
            m |= (v.w >= 0.1f ? 1u : 0u) << (q * 4 + 3);
        }
        PM[wi] = m;
    } else if (b < MASKB + 512) {
        const int idx = (b - MASKB) * 256 + tid;      // 131072 float4 slots
        if (idx < 65536) {
            float4 v = ((const float4*)Q)[idx];
            u16x4 o; o[0] = f2bf(v.x); o[1] = f2bf(v.y); o[2] = f2bf(v.z); o[3] = f2bf(v.w);
            ((u16x4*)Qbf)[idx] = o;
        } else {
            const int k = idx - 65536;
            float4 v = ((const float4*)Kf)[k];
            u16x4 o; o[0] = f2bf(v.x * KSCALE); o[1] = f2bf(v.y * KSCALE);
                     o[2] = f2bf(v.z * KSCALE); o[3] = f2bf(v.w * KSCALE);
            ((u16x4*)Kbf)[k] = o;
        }
    } else {
        const int j0 = (b - MASKB - 512) * 64;
#pragma unroll
        for (int it = 0; it < 4; ++it) {
            const int f4 = tid + it * 256;
            const int row = f4 >> 4, c4 = (f4 & 15) * 4;
            float4 v = *(const float4*)&V[(size_t)(j0 + row) * D + c4];
            tile[(c4 + 0) * 68 + row] = (short)f2bf(v.x);
            tile[(c4 + 1) * 68 + row] = (short)f2bf(v.y);
            tile[(c4 + 2) * 68 + row] = (short)f2bf(v.z);
            tile[(c4 + 3) * 68 + row] = (short)f2bf(v.w);
        }
        __syncthreads();
#pragma unroll
        for (int it = 0; it < 4; ++it) {
            const int f4 = tid + it * 256;
            const int d = f4 >> 4, o4 = (f4 & 15) * 4;
            u16x4 w = *(const u16x4*)&tile[d * 68 + o4];
            *(u16x4*)&VTbf[(size_t)d * S + j0 + o4] = w;
        }
    }
}

// ---- main ----
__launch_bounds__(256, 2)
__global__ void fused_main(const short* __restrict__ Qbf,
                           const short* __restrict__ Kbf,
                           const short* __restrict__ VTbf,
                           const unsigned* __restrict__ PM,
                           const float* __restrict__ RR,
                           float* __restrict__ Opart,            // [NCHUNK][S][D]
                           int* __restrict__ sumr)
{
    __shared__ short kb[2][16 * 512];    // K tile 128x64, fragment-major (frag=1KB)
    __shared__ short vb[16 * 512];       // V^T tile 64x128, fragment-major, SINGLE buf
    __shared__ short pb[4 * 16 * LDP];   // per-wave P relayout (16 x 128)
    __shared__ int red[4];

    const int tid  = threadIdx.x;
    const int w    = tid >> 6;
    const int lane = tid & 63;
    const int quad = lane >> 4;
    const int n16  = lane & 15;

    const int ib  = blockIdx.x & 63;
    const int ic  = blockIdx.x >> 6;     // 0..NCHUNK-1
    const int i0w = ib * 64 + w * 16;
    const int jbase = ic * JCHUNK;

    s16x8 aQ[2];
#pragma unroll
    for (int ks = 0; ks < 2; ++ks)
        aQ[ks] = *(const s16x8*)&Qbf[(size_t)(i0w + n16) * D + ks * 32 + quad * 8];

    float rr[4];
#pragma unroll
    for (int rg = 0; rg < 4; ++rg) rr[rg] = RR[i0w + quad * 4 + rg];

    f32x4 accO[4];
#pragma unroll
    for (int ds = 0; ds < 4; ++ds) accO[ds] = (f32x4){0.f, 0.f, 0.f, 0.f};

    float lsum = 0.f;
    short* pw = pb + w * 16 * LDP;

    // per-lane mask rows: row r = i0w + quad*4 + rg, 128 words/row
    const unsigned* pmr[4];
#pragma unroll
    for (int rg = 0; rg < 4; ++rg)
        pmr[rg] = PM + (size_t)(i0w + quad * 4 + rg) * (S / 32) + (jbase >> 5);

    i32x4 mk[2][4];                      // 128 mask bits per row per tile, dbuf

    // ---- prologue: tile 0 (mask first, then K, then V DMA) ----
    {
#pragma unroll
        for (int rg = 0; rg < 4; ++rg)
            mk[0][rg] = *(const i32x4*)pmr[rg];
#pragma unroll
        for (int p = 0; p < 4; ++p) {
            const int e = w * 4 + p;
            __builtin_amdgcn_global_load_lds(
                (g_u32*)&Kbf[(size_t)(jbase + (e >> 1) * 16 + n16) * D + (e & 1) * 32 + quad * 8],
                (lds_u32*)&kb[0][e * 512], 16, 0, 0);
        }
#pragma unroll
        for (int p = 0; p < 4; ++p) {
            const int e = w * 4 + p;
            __builtin_amdgcn_global_load_lds(
                (g_u32*)&VTbf[(size_t)((e & 3) * 16 + n16) * S + jbase + (e >> 2) * 32 + quad * 8],
                (lds_u32*)&vb[e * 512], 16, 0, 0);
        }
    }

#pragma unroll
    for (int jt = 0; jt < NTILES; ++jt) {
        const int bu = jt & 1;
        const int nb = bu ^ 1;
        const int j0 = jbase + jt * JT;
        const bool last = (jt + 1 == NTILES);

        // (a) NEXT tile: mask loads first, then K-DMA into kb[nb]
        if (!last) {
            const int j1 = j0 + JT;
#pragma unroll
            for (int rg = 0; rg < 4; ++rg)
                mk[nb][rg] = *(const i32x4*)(pmr[rg] + ((jt + 1) * (JT / 32)));
#pragma unroll
            for (int p = 0; p < 4; ++p) {
                const int e = w * 4 + p;
                __builtin_amdgcn_global_load_lds(
                    (g_u32*)&Kbf[(size_t)(j1 + (e >> 1) * 16 + n16) * D + (e & 1) * 32 + quad * 8],
                    (lds_u32*)&kb[nb][e * 512], 16, 0, 0);
            }
        }

        // (b) counted drain: the 8 youngest (mask(t+1) 4 + K(t+1) 4) may remain;
        //     everything older — K(t), V(t), mask(t) — must land.
        if (!last) { __asm__ volatile("s_waitcnt vmcnt(8)" ::: "memory"); }
        else       { __asm__ volatile("s_waitcnt vmcnt(0)" ::: "memory"); }
        __builtin_amdgcn_s_barrier();
        __asm__ volatile("" ::: "memory");

        // (c) QK^T + fused epilogue per 16-col subtile (accqk live = 4 regs)
#pragma unroll
        for (int cs = 0; cs < 8; ++cs) {
            f32x4 acc = (f32x4){0.f, 0.f, 0.f, 0.f};
#pragma unroll
            for (int ks = 0; ks < 2; ++ks) {
                s16x8 bK = *(const s16x8*)&kb[bu][(cs * 2 + ks) * 512 + lane * 8];
                acc = __builtin_amdgcn_mfma_f32_16x16x32_bf16(aQ[ks], bK, acc, 0, 0, 0);
            }
            const int wsel = cs >> 1;
            const int sh = (cs & 1) * 16 + n16;   // bit (cs*16+n16)&31 of word cs>>1
#pragma unroll
            for (int rg = 0; rg < 4; ++rg) {
                const unsigned word = (unsigned)mk[bu][rg][wsel];
                const float t = ((word >> sh) & 1u) ? acc[rg] : 0.0f;
                const float r = floorf(t * rr[rg]);
                lsum += r;
                pw[(quad * 4 + rg) * LDP + cs * 16 + n16] = (short)f2bf(t * r);
            }
        }

        // (d) within-wave LDS drain for pb
        __builtin_amdgcn_wave_barrier();
        __asm__ volatile("s_waitcnt lgkmcnt(0)" ::: "memory");
        __builtin_amdgcn_wave_barrier();

        // (e) PV over 128-wide contraction
#pragma unroll
        for (int ksj = 0; ksj < 4; ++ksj) {
            s16x8 aP = *(const s16x8*)&pw[n16 * LDP + ksj * 32 + quad * 8];
#pragma unroll
            for (int ds = 0; ds < 4; ++ds) {
                s16x8 bV = *(const s16x8*)&vb[(ksj * 4 + ds) * 512 + lane * 8];
                accO[ds] = __builtin_amdgcn_mfma_f32_16x16x32_bf16(aP, bV, accO[ds], 0, 0, 0);
            }
        }

        // (f) all waves past PV before vb is overwritten
        __asm__ volatile("" ::: "memory");
        __builtin_amdgcn_s_barrier();
        __asm__ volatile("" ::: "memory");

        // (g) issue V(t+1) into vb (single-buffered; landed-check = next vmcnt(8))
        if (!last) {
            const int j1 = j0 + JT;
#pragma unroll
            for (int p = 0; p < 4; ++p) {
                const int e = w * 4 + p;
                __builtin_amdgcn_global_load_lds(
                    (g_u32*)&VTbf[(size_t)((e & 3) * 16 + n16) * S + j1 + (e >> 2) * 32 + quad * 8],
                    (lds_u32*)&vb[e * 512], 16, 0, 0);
            }
        }
    }

    // deterministic partial stores (full 64B segments)
    float* op = Opart + (size_t)ic * S * D;
#pragma unroll
    for (int ds = 0; ds < 4; ++ds) {
        const int d = ds * 16 + n16;
#pragma unroll
        for (int rg = 0; rg < 4; ++rg) {
            const int i = i0w + quad * 4 + rg;
            op[(size_t)i * D + d] = accO[ds][rg];
        }
    }

    // sum(r): wave shuffle -> LDS -> one int atomic per block
    for (int off = 32; off; off >>= 1) lsum += __shfl_down(lsum, off);
    if (lane == 0) red[w] = (int)lsum;
    __syncthreads();
    if (tid == 0) atomicAdd(sumr, red[0] + red[1] + red[2] + red[3]);
}

// ---- reduce partials over NCHUNK + apply 1/R ----
__global__ void reduce_out(const float* __restrict__ Opart,
                           const int* __restrict__ sumr,
                           float* __restrict__ out) {
    const int idx = blockIdx.x * 256 + threadIdx.x;   // 65536 float4 groups
    const float invR = 1.0f / (float)(*sumr);         // |R| < 2^24: exact
    float sx = 0.f, sy = 0.f, sz = 0.f, sw = 0.f;
#pragma unroll
    for (int c = 0; c < NCHUNK; ++c) {
        const float4 v = ((const float4*)(Opart + (size_t)c * S * D))[idx];
        sx += v.x; sy += v.y; sz += v.z; sw += v.w;
    }
    float4 o; o.x = sx * invR; o.y = sy * invR; o.z = sz * invR; o.w = sw * invR;
    ((float4*)out)[idx] = o;
}

extern "C" void kernel_launch(void* const* d_in, const int* in_sizes, int n_in,
                              void* d_out, int out_size, void* d_ws, size_t ws_size,
                              hipStream_t stream) {
    (void)in_sizes; (void)n_in; (void)out_size; (void)ws_size;
    const float* Q  = (const float*)d_in[0];
    const float* Kf = (const float*)d_in[1];
    const float* V  = (const float*)d_in[2];
    const float* Ud = (const float*)d_in[3];
    const float* RR = (const float*)d_in[4];
    float* out = (float*)d_out;

    // ws layout: Opart 8MB | Qbf 512KB | Kbf 512KB | VTbf 512KB | sumr | PM 2MB
    char* ws = (char*)d_ws;
    float* Opart = (float*)ws;                                  // 8 MB
    short* Qbf  = (short*)(ws + (8u << 20));
    short* Kbf  = (short*)(ws + (8u << 20) + (512u << 10));
    short* VTbf = (short*)(ws + (8u << 20) + (1024u << 10));
    int*   sumr = (int*)  (ws + (8u << 20) + (1536u << 10));
    unsigned* PM = (unsigned*)(ws + (8u << 20) + (1664u << 10)); // 2 MB, 16B aligned

    prep_all<<<dim3(MASKB + 576), dim3(256), 0, stream>>>(Q, Kf, V, Ud, Qbf, Kbf, VTbf, PM, sumr);
    fused_main<<<dim3(64 * NCHUNK), dim3(256), 0, stream>>>(
        Qbf, Kbf, VTbf, PM, RR, Opart, sumr);
    reduce_out<<<dim3(256), dim3(256), 0, stream>>>(Opart, sumr, out);
}

// Round 2
// 123.618 us; speedup vs baseline: 1.0461x; 1.0461x over previous
//
#include <hip/hip_runtime.h>
#include <stdint.h>

// S=4096, D=64.  out = (t * floor(t*rr)/R) @ V,  t = (QK^T*8) * dropout_keep/0.9
// R14 = R12 (Ud streamed INSIDE fused_main, fully hidden under DMA/LDS stalls;
// R13 proved moving it to a serial prep pass costs +8us) with the Opart
// round-trip removed: fused_main atomically accumulates partials straight
// into out (1MB working set -> L2-resident atomics; replaces 8MB HBM write
// + 16.8MB read in reduce_out), prep_all zero-inits out, and a trivial
// scale_out kernel applies 1/R at the end (2MB traffic vs 17MB).

#define S 4096
#define D 64
#define NCHUNK 8              // grid = 64 i-blocks * 8 chunks = 512 blocks
#define JCHUNK (S / NCHUNK)   // 512
#define JT 128
#define NTILES (JCHUNK / JT)  // 4
#define LDP 132               // pb pitch (shorts): 4 quads -> 4 distinct bank groups
#define KSCALE (8.0f / 0.9f)

typedef float f32x4 __attribute__((ext_vector_type(4)));
typedef short s16x8 __attribute__((ext_vector_type(8)));
typedef unsigned short u16x4 __attribute__((ext_vector_type(4)));
typedef const __attribute__((address_space(1))) unsigned g_u32;
typedef __attribute__((address_space(3))) unsigned lds_u32;

__device__ inline unsigned short f2bf(float f) {
    union { float f; unsigned u; } v; v.f = f;
    unsigned r = v.u + 0x7fffu + ((v.u >> 16) & 1u);
    return (unsigned short)(r >> 16);
}

// ---- prep: Q->bf16, K->bf16*KSCALE (blocks 0..511), V->V^T (512..575),
//      blocks 0..255 additionally zero-init out (1MB) for atomic accumulation
__global__ void prep_all(const float* __restrict__ Q,
                         const float* __restrict__ Kf,
                         const float* __restrict__ V,
                         short* __restrict__ Qbf, short* __restrict__ Kbf,
                         short* __restrict__ VTbf, int* __restrict__ sumr,
                         float* __restrict__ out) {
    __shared__ short tile[64 * 68];
    const int b   = blockIdx.x;
    const int tid = threadIdx.x;
    if (b == 0 && tid == 0) *sumr = 0;

    if (b < 256) {
        // zero out[] : 65536 float4 groups over 256 blocks
        ((float4*)out)[b * 256 + tid] = (float4){0.f, 0.f, 0.f, 0.f};
    }

    if (b < 512) {
        const int idx = b * 256 + tid;               // 131072 float4 slots
        if (idx < 65536) {
            float4 v = ((const float4*)Q)[idx];
            u16x4 o; o[0] = f2bf(v.x); o[1] = f2bf(v.y); o[2] = f2bf(v.z); o[3] = f2bf(v.w);
            ((u16x4*)Qbf)[idx] = o;
        } else {
            const int k = idx - 65536;
            float4 v = ((const float4*)Kf)[k];
            u16x4 o; o[0] = f2bf(v.x * KSCALE); o[1] = f2bf(v.y * KSCALE);
                     o[2] = f2bf(v.z * KSCALE); o[3] = f2bf(v.w * KSCALE);
            ((u16x4*)Kbf)[k] = o;
        }
    } else {
        const int j0 = (b - 512) * 64;
#pragma unroll
        for (int it = 0; it < 4; ++it) {
            const int f4 = tid + it * 256;
            const int row = f4 >> 4, c4 = (f4 & 15) * 4;
            float4 v = *(const float4*)&V[(size_t)(j0 + row) * D + c4];
            tile[(c4 + 0) * 68 + row] = (short)f2bf(v.x);
            tile[(c4 + 1) * 68 + row] = (short)f2bf(v.y);
            tile[(c4 + 2) * 68 + row] = (short)f2bf(v.z);
            tile[(c4 + 3) * 68 + row] = (short)f2bf(v.w);
        }
        __syncthreads();
#pragma unroll
        for (int it = 0; it < 4; ++it) {
            const int f4 = tid + it * 256;
            const int d = f4 >> 4, o4 = (f4 & 15) * 4;
            u16x4 w = *(const u16x4*)&tile[d * 68 + o4];
            *(u16x4*)&VTbf[(size_t)d * S + j0 + o4] = w;
        }
    }
}

// ---- main ----
__launch_bounds__(256, 2)
__global__ void fused_main(const short* __restrict__ Qbf,
                           const short* __restrict__ Kbf,
                           const short* __restrict__ VTbf,
                           const float* __restrict__ Ud,
                           const float* __restrict__ RR,
                           float* __restrict__ out,              // atomic accum
                           int* __restrict__ sumr)
{
    __shared__ short kb[2][16 * 512];    // K tile 128x64, fragment-major (frag=1KB)
    __shared__ short vb[16 * 512];       // V^T tile 64x128, fragment-major, SINGLE buf
    __shared__ short pb[4 * 16 * LDP];   // per-wave P relayout (16 x 128)
    __shared__ int red[4];

    const int tid  = threadIdx.x;
    const int w    = tid >> 6;
    const int lane = tid & 63;
    const int quad = lane >> 4;
    const int n16  = lane & 15;

    const int ib  = blockIdx.x & 63;
    const int ic  = blockIdx.x >> 6;     // 0..NCHUNK-1
    const int i0w = ib * 64 + w * 16;
    const int jbase = ic * JCHUNK;

    const float* uwb = Ud + (size_t)i0w * S;

    s16x8 aQ[2];
#pragma unroll
    for (int ks = 0; ks < 2; ++ks)
        aQ[ks] = *(const s16x8*)&Qbf[(size_t)(i0w + n16) * D + ks * 32 + quad * 8];

    float rr[4];
#pragma unroll
    for (int rg = 0; rg < 4; ++rg) rr[rg] = RR[i0w + quad * 4 + rg];

    f32x4 accO[4];
#pragma unroll
    for (int ds = 0; ds < 4; ++ds) accO[ds] = (f32x4){0.f, 0.f, 0.f, 0.f};

    float lsum = 0.f;
    short* pw = pb + w * 16 * LDP;

    unsigned um[2];                        // 32 keep-bits per lane per tile
    const int bsel  = quad * 4 + (n16 & 3);      // + h*16 at use
    const int bidx0 = (n16 >> 2) * 4;

    // ---- prologue: tile 0 (u first, then K, then V; pack last) ----
    float4 un[8];
    {
        const int j0 = jbase;
#pragma unroll
        for (int h = 0; h < 2; ++h)
#pragma unroll
            for (int q = 0; q < 4; ++q)
                un[h * 4 + q] = *(const float4*)&uwb[(size_t)(q * 4 + quad) * S + j0 + h * 64 + n16 * 4];
#pragma unroll
        for (int p = 0; p < 4; ++p) {
            const int e = w * 4 + p;
            __builtin_amdgcn_global_load_lds(
                (g_u32*)&Kbf[(size_t)(j0 + (e >> 1) * 16 + n16) * D + (e & 1) * 32 + quad * 8],
                (lds_u32*)&kb[0][e * 512], 16, 0, 0);
        }
#pragma unroll
        for (int p = 0; p < 4; ++p) {
            const int e = w * 4 + p;
            __builtin_amdgcn_global_load_lds(
                (g_u32*)&VTbf[(size_t)((e & 3) * 16 + n16) * S + j0 + (e >> 2) * 32 + quad * 8],
                (lds_u32*)&vb[e * 512], 16, 0, 0);
        }
        unsigned m = 0;
#pragma unroll
        for (int e = 0; e < 8; ++e) {     // pack waits u0; K0/V0 (younger) stay in flight
            m |= (un[e].x >= 0.1f ? 1u : 0u) << (e * 4 + 0);
            m |= (un[e].y >= 0.1f ? 1u : 0u) << (e * 4 + 1);
            m |= (un[e].z >= 0.1f ? 1u : 0u) << (e * 4 + 2);
            m |= (un[e].w >= 0.1f ? 1u : 0u) << (e * 4 + 3);
        }
        um[0] = m;
    }

#pragma unroll
    for (int jt = 0; jt < NTILES; ++jt) {
        const int bu = jt & 1;
        const int nb = bu ^ 1;
        const int j0 = jbase + jt * JT;
        const bool last = (jt + 1 == NTILES);

        // (a) NEXT tile: u loads first, then K-DMA into kb[nb]
        if (!last) {
            const int j1 = j0 + JT;
#pragma unroll
            for (int h = 0; h < 2; ++h)
#pragma unroll
                for (int q = 0; q < 4; ++q)
                    un[h * 4 + q] = *(const float4*)&uwb[(size_t)(q * 4 + quad) * S + j1 + h * 64 + n16 * 4];
#pragma unroll
            for (int p = 0; p < 4; ++p) {
                const int e = w * 4 + p;
                __builtin_amdgcn_global_load_lds(
                    (g_u32*)&Kbf[(size_t)(j1 + (e >> 1) * 16 + n16) * D + (e & 1) * 32 + quad * 8],
                    (lds_u32*)&kb[nb][e * 512], 16, 0, 0);
            }
        }

        // (b) counted drain: the 12 youngest (u(t+1) 8 + K(t+1) 4) may remain;
        //     everything older — K(t), V(t), stragglers — must land.
        if (!last) { __asm__ volatile("s_waitcnt vmcnt(12)" ::: "memory"); }
        else       { __asm__ volatile("s_waitcnt vmcnt(0)"  ::: "memory"); }
        __builtin_amdgcn_s_barrier();
        __asm__ volatile("" ::: "memory");

        // (c) QK^T + fused epilogue per 16-col subtile (accqk live = 4 regs)
#pragma unroll
        for (int cs = 0; cs < 8; ++cs) {
            f32x4 acc = (f32x4){0.f, 0.f, 0.f, 0.f};
#pragma unroll
            for (int ks = 0; ks < 2; ++ks) {
                s16x8 bK = *(const s16x8*)&kb[bu][(cs * 2 + ks) * 512 + lane * 8];
                acc = __builtin_amdgcn_mfma_f32_16x16x32_bf16(aQ[ks], bK, acc, 0, 0, 0);
            }
            const int h = cs >> 2, c4 = cs & 3;
#pragma unroll
            for (int rg = 0; rg < 4; ++rg) {
                const int mv = __builtin_amdgcn_ds_bpermute(
                    (rg * 16 + c4 * 4) * 4 + bidx0, (int)um[bu]);
                const float t = ((((unsigned)mv) >> (h * 16 + bsel)) & 1u) ? acc[rg] : 0.0f;
                const float r = floorf(t * rr[rg]);
                lsum += r;
                pw[(quad * 4 + rg) * LDP + cs * 16 + n16] = (short)f2bf(t * r);
            }
        }

        // (d) within-wave LDS drain for pb
        __builtin_amdgcn_wave_barrier();
        __asm__ volatile("s_waitcnt lgkmcnt(0)" ::: "memory");
        __builtin_amdgcn_wave_barrier();

        // (e) PV over 128-wide contraction
#pragma unroll
        for (int ksj = 0; ksj < 4; ++ksj) {
            s16x8 aP = *(const s16x8*)&pw[n16 * LDP + ksj * 32 + quad * 8];
#pragma unroll
            for (int ds = 0; ds < 4; ++ds) {
                s16x8 bV = *(const s16x8*)&vb[(ksj * 4 + ds) * 512 + lane * 8];
                accO[ds] = __builtin_amdgcn_mfma_f32_16x16x32_bf16(aP, bV, accO[ds], 0, 0, 0);
            }
        }

        // (f) all waves past PV before vb is overwritten
        __asm__ volatile("" ::: "memory");
        __builtin_amdgcn_s_barrier();
        __asm__ volatile("" ::: "memory");

        // (g) pack u(t+1) (waits only u regs), THEN issue V(t+1) into vb
        if (!last) {
            unsigned m = 0;
#pragma unroll
            for (int e = 0; e < 8; ++e) {
                m |= (un[e].x >= 0.1f ? 1u : 0u) << (e * 4 + 0);
                m |= (un[e].y >= 0.1f ? 1u : 0u) << (e * 4 + 1);
                m |= (un[e].z >= 0.1f ? 1u : 0u) << (e * 4 + 2);
                m |= (un[e].w >= 0.1f ? 1u : 0u) << (e * 4 + 3);
            }
            um[nb] = m;
            const int j1 = j0 + JT;
#pragma unroll
            for (int p = 0; p < 4; ++p) {
                const int e = w * 4 + p;
                __builtin_amdgcn_global_load_lds(
                    (g_u32*)&VTbf[(size_t)((e & 3) * 16 + n16) * S + j1 + (e >> 2) * 32 + quad * 8],
                    (lds_u32*)&vb[e * 512], 16, 0, 0);
            }
        }
    }

    // atomic accumulation straight into out (pre-zeroed by prep_all).
    // 1MB target -> L2-resident; replaces the 8MB Opart write + 17MB reduce.
#pragma unroll
    for (int ds = 0; ds < 4; ++ds) {
        const int d = ds * 16 + n16;
#pragma unroll
        for (int rg = 0; rg < 4; ++rg) {
            const int i = i0w + quad * 4 + rg;
            atomicAdd(&out[(size_t)i * D + d], accO[ds][rg]);
        }
    }

    // sum(r): wave shuffle -> LDS -> one int atomic per block
    for (int off = 32; off; off >>= 1) lsum += __shfl_down(lsum, off);
    if (lane == 0) red[w] = (int)lsum;
    __syncthreads();
    if (tid == 0) atomicAdd(sumr, red[0] + red[1] + red[2] + red[3]);
}

// ---- apply 1/R in place ----
__global__ void scale_out(const int* __restrict__ sumr,
                          float* __restrict__ out) {
    const int idx = blockIdx.x * 256 + threadIdx.x;   // 65536 float4 groups
    const float invR = 1.0f / (float)(*sumr);         // |R| < 2^24: exact
    float4 v = ((const float4*)out)[idx];
    v.x *= invR; v.y *= invR; v.z *= invR; v.w *= invR;
    ((float4*)out)[idx] = v;
}

extern "C" void kernel_launch(void* const* d_in, const int* in_sizes, int n_in,
                              void* d_out, int out_size, void* d_ws, size_t ws_size,
                              hipStream_t stream) {
    (void)in_sizes; (void)n_in; (void)out_size; (void)ws_size;
    const float* Q  = (const float*)d_in[0];
    const float* Kf = (const float*)d_in[1];
    const float* V  = (const float*)d_in[2];
    const float* Ud = (const float*)d_in[3];
    const float* RR = (const float*)d_in[4];
    float* out = (float*)d_out;

    // ws layout: Qbf 512KB | Kbf 512KB | VTbf 512KB | sumr
    char* ws = (char*)d_ws;
    short* Qbf  = (short*)ws;
    short* Kbf  = (short*)(ws + (512u << 10));
    short* VTbf = (short*)(ws + (1024u << 10));
    int*   sumr = (int*)  (ws + (1536u << 10));

    prep_all<<<dim3(576), dim3(256), 0, stream>>>(Q, Kf, V, Qbf, Kbf, VTbf, sumr, out);
    fused_main<<<dim3(64 * NCHUNK), dim3(256), 0, stream>>>(
        Qbf, Kbf, VTbf, Ud, RR, out, sumr);
    scale_out<<<dim3(256), dim3(256), 0, stream>>>(sumr, out);
}

// Round 4
// 120.895 us; speedup vs baseline: 1.0696x; 1.0225x over previous
//
#include <hip/hip_runtime.h>
#include <stdint.h>

// S=4096, D=64.  out = (t * floor(t*rr)/R) @ V,  t = (QK^T*8) * dropout_keep/0.9
// R16 = R15 resubmitted (R3 bench died at container level, no verdict; kernel
// math re-audited: barrier uniformity, vmcnt counts, P-transpose mapping all
// verified). R15 = R12 base (Opart + reduce_out, no atomics) with
// SWAPPED-OPERAND QK^T: mfma(K,Q) instead of mfma(Q,K). A/B fragments of
// 16x16x32 have identical per-lane layouts, so the swap is free and gives lane
// (quad,n16) the P values for i=n16, j=16cs+4quad+rg. This makes the dropout
// mask lane-local (bit cs*4+rg of a per-lane word: the 32 mask bpermutes die),
// and replaces the pb LDS round-trip (32 ds_write + 4 ds_read_b128 + lgkm
// drain) with an in-register redistribution: 16 v_cvt_pk_bf16_f32 + 32
// ds_bpermute + 16 cndmask. pb's 16.9KB freed -> vb DOUBLE-buffered ->
// single-barrier-per-tile schedule: issue K/V(t+1) at tile top, counted
// vmcnt(8) + barrier at tile end (V latency hidden under a full tile).
// Barriers 8 -> 4 per block.

#define S 4096
#define D 64
#define NCHUNK 8              // grid = 64 i-blocks * 8 chunks = 512 blocks
#define JCHUNK (S / NCHUNK)   // 512
#define JT 128
#define NTILES (JCHUNK / JT)  // 4
#define KSCALE (8.0f / 0.9f)

typedef float f32x4 __attribute__((ext_vector_type(4)));
typedef short s16x8 __attribute__((ext_vector_type(8)));
typedef unsigned short u16x4 __attribute__((ext_vector_type(4)));
typedef int i32x4 __attribute__((ext_vector_type(4)));
typedef const __attribute__((address_space(1))) unsigned g_u32;
typedef __attribute__((address_space(3))) unsigned lds_u32;

__device__ inline unsigned short f2bf(float f) {
    union { float f; unsigned u; } v; v.f = f;
    unsigned r = v.u + 0x7fffu + ((v.u >> 16) & 1u);
    return (unsigned short)(r >> 16);
}

__device__ inline unsigned cvt_pk_bf16(float lo, float hi) {
    unsigned r;
    asm("v_cvt_pk_bf16_f32 %0, %1, %2" : "=v"(r) : "v"(lo), "v"(hi));
    return r;   // [15:0]=bf16(lo), [31:16]=bf16(hi)
}

// ---- prep: Q->bf16, K->bf16*KSCALE (blocks 0..511), V->V^T (512..575) ----
__global__ void prep_all(const float* __restrict__ Q,
                         const float* __restrict__ Kf,
                         const float* __restrict__ V,
                         short* __restrict__ Qbf, short* __restrict__ Kbf,
                         short* __restrict__ VTbf, int* __restrict__ sumr) {
    __shared__ short tile[64 * 68];
    const int b   = blockIdx.x;
    const int tid = threadIdx.x;
    if (b == 0 && tid == 0) *sumr = 0;

    if (b < 512) {
        const int idx = b * 256 + tid;               // 131072 float4 slots
        if (idx < 65536) {
            float4 v = ((const float4*)Q)[idx];
            u16x4 o; o[0] = f2bf(v.x); o[1] = f2bf(v.y); o[2] = f2bf(v.z); o[3] = f2bf(v.w);
            ((u16x4*)Qbf)[idx] = o;
        } else {
            const int k = idx - 65536;
            float4 v = ((const float4*)Kf)[k];
            u16x4 o; o[0] = f2bf(v.x * KSCALE); o[1] = f2bf(v.y * KSCALE);
                     o[2] = f2bf(v.z * KSCALE); o[3] = f2bf(v.w * KSCALE);
            ((u16x4*)Kbf)[k] = o;
        }
    } else {
        const int j0 = (b - 512) * 64;
#pragma unroll
        for (int it = 0; it < 4; ++it) {
            const int f4 = tid + it * 256;
            const int row = f4 >> 4, c4 = (f4 & 15) * 4;
            float4 v = *(const float4*)&V[(size_t)(j0 + row) * D + c4];
            tile[(c4 + 0) * 68 + row] = (short)f2bf(v.x);
            tile[(c4 + 1) * 68 + row] = (short)f2bf(v.y);
            tile[(c4 + 2) * 68 + row] = (short)f2bf(v.z);
            tile[(c4 + 3) * 68 + row] = (short)f2bf(v.w);
        }
        __syncthreads();
#pragma unroll
        for (int it = 0; it < 4; ++it) {
            const int f4 = tid + it * 256;
            const int d = f4 >> 4, o4 = (f4 & 15) * 4;
            u16x4 w = *(const u16x4*)&tile[d * 68 + o4];
            *(u16x4*)&VTbf[(size_t)d * S + j0 + o4] = w;
        }
    }
}

// ---- main ----
__launch_bounds__(256, 2)
__global__ void fused_main(const short* __restrict__ Qbf,
                           const short* __restrict__ Kbf,
                           const short* __restrict__ VTbf,
                           const float* __restrict__ Ud,
                           const float* __restrict__ RR,
                           float* __restrict__ Opart,            // [NCHUNK][S][D]
                           int* __restrict__ sumr)
{
    __shared__ short kb[2][16 * 512];    // K tile 128x64, fragment-major (frag=1KB)
    __shared__ short vb[2][16 * 512];    // V^T tile 64x128, fragment-major, DBUF
    __shared__ int red[4];

    const int tid  = threadIdx.x;
    const int w    = tid >> 6;
    const int lane = tid & 63;
    const int quad = lane >> 4;
    const int n16  = lane & 15;

    const int ib  = blockIdx.x & 63;
    const int ic  = blockIdx.x >> 6;     // 0..NCHUNK-1
    const int i0w = ib * 64 + w * 16;
    const int jbase = ic * JCHUNK;

    // dropout row for THIS lane (i = i0w + n16), starting at its quad's 4 cols
    const float* uln = Ud + (size_t)(i0w + n16) * S + quad * 4;

    s16x8 aQ[2];
#pragma unroll
    for (int ks = 0; ks < 2; ++ks)
        aQ[ks] = *(const s16x8*)&Qbf[(size_t)(i0w + n16) * D + ks * 32 + quad * 8];

    const float rrn = RR[i0w + n16];     // single row_rand per lane (row = n16)

    f32x4 accO[4];
#pragma unroll
    for (int ds = 0; ds < 4; ++ds) accO[ds] = (f32x4){0.f, 0.f, 0.f, 0.f};

    float lsum = 0.f;
    float4 un[8];                        // u(t): row n16, cols 16c+4quad+0..3
    unsigned um;                         // 32 keep-bits, bit index c*4+r

    // ---- prologue: K0,V0 DMA + u0 loads; drain K0/V0; barrier ----
    {
#pragma unroll
        for (int p = 0; p < 4; ++p) {
            const int e = w * 4 + p;
            __builtin_amdgcn_global_load_lds(
                (g_u32*)&Kbf[(size_t)(jbase + (e >> 1) * 16 + n16) * D + (e & 1) * 32 + quad * 8],
                (lds_u32*)&kb[0][e * 512], 16, 0, 0);
        }
#pragma unroll
        for (int p = 0; p < 4; ++p) {
            const int e = w * 4 + p;
            __builtin_amdgcn_global_load_lds(
                (g_u32*)&VTbf[(size_t)((e & 3) * 16 + n16) * S + jbase + (e >> 2) * 32 + quad * 8],
                (lds_u32*)&vb[0][e * 512], 16, 0, 0);
        }
#pragma unroll
        for (int c = 0; c < 8; ++c)
            un[c] = *(const float4*)&uln[jbase + c * 16];
        __asm__ volatile("s_waitcnt vmcnt(8)" ::: "memory");   // K0,V0 landed; u0 may fly
        __builtin_amdgcn_s_barrier();
        __asm__ volatile("" ::: "memory");
    }

#pragma unroll
    for (int jt = 0; jt < NTILES; ++jt) {
        const int bu = jt & 1;
        const int nb = bu ^ 1;
        const bool last = (jt + 1 == NTILES);

        // (a) issue NEXT tile K/V DMA (into nb; safe: end-of-prev barrier passed)
        if (!last) {
            const int j1 = jbase + (jt + 1) * JT;
#pragma unroll
            for (int p = 0; p < 4; ++p) {
                const int e = w * 4 + p;
                __builtin_amdgcn_global_load_lds(
                    (g_u32*)&Kbf[(size_t)(j1 + (e >> 1) * 16 + n16) * D + (e & 1) * 32 + quad * 8],
                    (lds_u32*)&kb[nb][e * 512], 16, 0, 0);
            }
#pragma unroll
            for (int p = 0; p < 4; ++p) {
                const int e = w * 4 + p;
                __builtin_amdgcn_global_load_lds(
                    (g_u32*)&VTbf[(size_t)((e & 3) * 16 + n16) * S + j1 + (e >> 2) * 32 + quad * 8],
                    (lds_u32*)&vb[nb][e * 512], 16, 0, 0);
            }
        }

        // (b) pack u(t) -> um (compiler-counted wait drains only u(t); the K/V
        //     DMAs just issued stay in flight), then load u(t+1)
        {
            unsigned m = 0;
#pragma unroll
            for (int c = 0; c < 8; ++c) {
                m |= (un[c].x >= 0.1f ? 1u : 0u) << (c * 4 + 0);
                m |= (un[c].y >= 0.1f ? 1u : 0u) << (c * 4 + 1);
                m |= (un[c].z >= 0.1f ? 1u : 0u) << (c * 4 + 2);
                m |= (un[c].w >= 0.1f ? 1u : 0u) << (c * 4 + 3);
            }
            um = m;
        }
        if (!last) {
            const int j1 = jbase + (jt + 1) * JT;
#pragma unroll
            for (int c = 0; c < 8; ++c)
                un[c] = *(const float4*)&uln[j1 + c * 16];
        }

        // (c) swapped QK^T + lane-local epilogue: acc[rg] = P[i=n16][j=16cs+4quad+rg]
        unsigned pkw[16];                // bf16-pair words: pkw[c*2+m] = (val[2m],val[2m+1])
#pragma unroll
        for (int cs = 0; cs < 8; ++cs) {
            f32x4 acc = (f32x4){0.f, 0.f, 0.f, 0.f};
#pragma unroll
            for (int ks = 0; ks < 2; ++ks) {
                s16x8 bK = *(const s16x8*)&kb[bu][(cs * 2 + ks) * 512 + lane * 8];
                acc = __builtin_amdgcn_mfma_f32_16x16x32_bf16(bK, aQ[ks], acc, 0, 0, 0);
            }
            float vv[4];
#pragma unroll
            for (int rg = 0; rg < 4; ++rg) {
                const float t = ((um >> (cs * 4 + rg)) & 1u) ? acc[rg] : 0.0f;
                const float r = floorf(t * rrn);
                lsum += r;
                vv[rg] = t * r;
            }
            pkw[cs * 2]     = cvt_pk_bf16(vv[0], vv[1]);
            pkw[cs * 2 + 1] = cvt_pk_bf16(vv[2], vv[3]);
        }

        // (e) in-register P transpose (bpermute within n16-columns) + PV.
        // target aP word widx of ksj = pk-word [4ksj + 2*(q>=2) + (widx&1)]
        // of lane (2*(q&1) + (widx>>1))*16 + n16.
        const int pbase = (32 * ((lane >> 4) & 1) + n16) * 4;
#pragma unroll
        for (int ksj = 0; ksj < 4; ++ksj) {
            i32x4 aw;
#pragma unroll
            for (int widx = 0; widx < 4; ++widx) {
                const int addr = pbase + (widx >> 1) * 64;
                const int lo = __builtin_amdgcn_ds_bpermute(addr, (int)pkw[ksj * 4 + (widx & 1)]);
                const int hi = __builtin_amdgcn_ds_bpermute(addr, (int)pkw[ksj * 4 + 2 + (widx & 1)]);
                aw[widx] = (lane >= 32) ? hi : lo;
            }
            s16x8 aP;
            __builtin_memcpy(&aP, &aw, 16);
#pragma unroll
            for (int ds = 0; ds < 4; ++ds) {
                s16x8 bV = *(const s16x8*)&vb[bu][(ksj * 4 + ds) * 512 + lane * 8];
                accO[ds] = __builtin_amdgcn_mfma_f32_16x16x32_bf16(aP, bV, accO[ds], 0, 0, 0);
            }
        }

        // (f) end-of-tile: drain K/V(t+1) (u(t+1) 8 youngest may fly); barrier
        //     guards both landing (for t+1 reads) and bu-buffer reuse (t+2 DMA).
        if (!last) {
            __asm__ volatile("s_waitcnt vmcnt(8)" ::: "memory");
            __builtin_amdgcn_s_barrier();
            __asm__ volatile("" ::: "memory");
        }
    }

    // deterministic partial stores (full 64B segments)
    float* op = Opart + (size_t)ic * S * D;
#pragma unroll
    for (int ds = 0; ds < 4; ++ds) {
        const int d = ds * 16 + n16;
#pragma unroll
        for (int rg = 0; rg < 4; ++rg) {
            const int i = i0w + quad * 4 + rg;
            op[(size_t)i * D + d] = accO[ds][rg];
        }
    }

    // sum(r): wave shuffle -> LDS -> one int atomic per block
    for (int off = 32; off; off >>= 1) lsum += __shfl_down(lsum, off);
    if (lane == 0) red[w] = (int)lsum;
    __syncthreads();
    if (tid == 0) atomicAdd(sumr, red[0] + red[1] + red[2] + red[3]);
}

// ---- reduce partials over NCHUNK + apply 1/R ----
__global__ void reduce_out(const float* __restrict__ Opart,
                           const int* __restrict__ sumr,
                           float* __restrict__ out) {
    const int idx = blockIdx.x * 256 + threadIdx.x;   // 65536 float4 groups
    const float invR = 1.0f / (float)(*sumr);         // |R| < 2^24: exact
    float sx = 0.f, sy = 0.f, sz = 0.f, sw = 0.f;
#pragma unroll
    for (int c = 0; c < NCHUNK; ++c) {
        const float4 v = ((const float4*)(Opart + (size_t)c * S * D))[idx];
        sx += v.x; sy += v.y; sz += v.z; sw += v.w;
    }
    float4 o; o.x = sx * invR; o.y = sy * invR; o.z = sz * invR; o.w = sw * invR;
    ((float4*)out)[idx] = o;
}

extern "C" void kernel_launch(void* const* d_in, const int* in_sizes, int n_in,
                              void* d_out, int out_size, void* d_ws, size_t ws_size,
                              hipStream_t stream) {
    (void)in_sizes; (void)n_in; (void)out_size; (void)ws_size;
    const float* Q  = (const float*)d_in[0];
    const float* Kf = (const float*)d_in[1];
    const float* V  = (const float*)d_in[2];
    const float* Ud = (const float*)d_in[3];
    const float* RR = (const float*)d_in[4];
    float* out = (float*)d_out;

    // ws layout: Opart 8MB | Qbf 512KB | Kbf 512KB | VTbf 512KB | sumr
    char* ws = (char*)d_ws;
    float* Opart = (float*)ws;                                  // 8 MB
    short* Qbf  = (short*)(ws + (8u << 20));
    short* Kbf  = (short*)(ws + (8u << 20) + (512u << 10));
    short* VTbf = (short*)(ws + (8u << 20) + (1024u << 10));
    int*   sumr = (int*)  (ws + (8u << 20) + (1536u << 10));

    prep_all<<<dim3(576), dim3(256), 0, stream>>>(Q, Kf, V, Qbf, Kbf, VTbf, sumr);
    fused_main<<<dim3(64 * NCHUNK), dim3(256), 0, stream>>>(
        Qbf, Kbf, VTbf, Ud, RR, Opart, sumr);
    reduce_out<<<dim3(256), dim3(256), 0, stream>>>(Opart, sumr, out);
}